// Round 1
// baseline (54.137 us; speedup 1.0000x reference)
//
#include <hip/hip_runtime.h>
#include <hip/hip_bf16.h>

// Problem constants (fixed by setup_inputs: num_views=8, bs=4096, c=2048).
#define NV   8
#define BSZ  4096
#define CCH  2048
#define NPAIR 28          // NV*(NV-1)/2
#define NACC  36          // NV*(NV+1)/2 (upper triangle incl. diagonal)
#define BLK  256

// index of (v,w), v<=w, in the packed upper-triangular enumeration
__device__ __forceinline__ constexpr int triIdx(int v, int w) {
    return v * NV - (v * (v - 1)) / 2 + (w - v);
}

__global__ __launch_bounds__(BLK) void interviews_kernel(
        const float* __restrict__ in, float* __restrict__ out) {
    const int b = blockIdx.x;     // batch row, 0..BSZ-1
    const int t = threadIdx.x;

    float acc[NACC];
#pragma unroll
    for (int i = 0; i < NACC; ++i) acc[i] = 0.0f;

    // view v, batch b, channel c lives at in[v*BSZ*CCH + b*CCH + c]
    const float* base = in + (size_t)b * CCH;

    // 2048 channels / (256 threads * 4 floats) = 2 iterations
#pragma unroll
    for (int j = 0; j < CCH / (BLK * 4); ++j) {
        float4 x[NV];
#pragma unroll
        for (int v = 0; v < NV; ++v) {
            const float* p = base + (size_t)v * BSZ * CCH + (size_t)j * BLK * 4 + (size_t)t * 4;
            x[v] = *reinterpret_cast<const float4*>(p);
        }
        int idx = 0;
#pragma unroll
        for (int v = 0; v < NV; ++v) {
#pragma unroll
            for (int w = v; w < NV; ++w) {
                acc[idx] += x[v].x * x[w].x + x[v].y * x[w].y
                          + x[v].z * x[w].z + x[v].w * x[w].w;
                ++idx;
            }
        }
    }

    // wave-level tree reduction (wave = 64 lanes)
#pragma unroll
    for (int i = 0; i < NACC; ++i) {
        float v = acc[i];
#pragma unroll
        for (int off = 32; off > 0; off >>= 1)
            v += __shfl_down(v, off, 64);
        acc[i] = v;
    }

    __shared__ float red[BLK / 64][NACC];
    const int wave = t >> 6;
    const int lane = t & 63;
    if (lane == 0) {
#pragma unroll
        for (int i = 0; i < NACC; ++i) red[wave][i] = acc[i];
    }
    __syncthreads();

    if (t == 0) {
        float G[NACC];
#pragma unroll
        for (int i = 0; i < NACC; ++i)
            G[i] = red[0][i] + red[1][i] + red[2][i] + red[3][i];

        float rn[NV];
#pragma unroll
        for (int v = 0; v < NV; ++v)
            rn[v] = 1.0f / sqrtf(G[triIdx(v, v)]);

        float s[NPAIR];
        float mean = 0.0f;
        int k = 0;
#pragma unroll
        for (int v = 0; v < NV; ++v) {
#pragma unroll
            for (int w = v + 1; w < NV; ++w) {
                s[k] = G[triIdx(v, w)] * rn[v] * rn[w];
                mean += s[k];
                ++k;
            }
        }
        mean *= (1.0f / NPAIR);

        float var = 0.0f;
#pragma unroll
        for (int i = 0; i < NPAIR; ++i) {
            float d = s[i] - mean;
            var += d * d;
        }
        var *= (1.0f / (NPAIR - 1));   // ddof=1

        out[b] = -var;
    }
}

extern "C" void kernel_launch(void* const* d_in, const int* in_sizes, int n_in,
                              void* d_out, int out_size, void* d_ws, size_t ws_size,
                              hipStream_t stream) {
    const float* in = (const float*)d_in[0];
    float* out = (float*)d_out;
    // out_size == BSZ (4096); one block per batch row
    interviews_kernel<<<dim3(out_size), dim3(BLK), 0, stream>>>(in, out);
}